// Round 4
// baseline (491.437 us; speedup 1.0000x reference)
//
#include <hip/hip_runtime.h>
#include <cstdint>
#include <cstddef>

#define NI   256
#define QKC  32
#define BS   4
#define NPIX 4096   // 64*64

typedef __bf16 bf16x8 __attribute__((ext_vector_type(8)));
typedef float  f32x16 __attribute__((ext_vector_type(16)));

__device__ inline f32x16 zero16() {
    f32x16 z;
    #pragma unroll
    for (int i = 0; i < 16; ++i) z[i] = 0.f;
    return z;
}

// ---------------- Kernel 0: W fp32 -> bf16, concat [320][256] ----------------
__global__ __launch_bounds__(256) void wconv(
    const float* __restrict__ wq, const float* __restrict__ wk,
    const float* __restrict__ wv, __bf16* __restrict__ wbf)
{
    int f = (blockIdx.x * 256 + threadIdx.x) * 4;   // 0..81916
    int row = f >> 8, c = f & 255;
    const float* src = row < 32 ? wq + row * NI + c
                     : row < 64 ? wk + (row - 32) * NI + c
                                : wv + (row - 64) * NI + c;
    float4 v = *(const float4*)src;
    __align__(8) __bf16 o4[4] = {(__bf16)v.x, (__bf16)v.y, (__bf16)v.z, (__bf16)v.w};
    *(uint2*)(wbf + f) = *(const uint2*)o4;
}

// ---------------- Kernel 1: QKV projection as bf16 MFMA GEMM ----------------
// out[320][4096] = W[320][256] x x[256][4096] per batch.
// q (och 0..31), k (32..63): C[n][och] tiles -> hi/lo split, stored [b][n][32]
// v (64..319):              C[och][n] tiles -> bf16 [b][c][n]
// Both tile kinds use identical LDS fragment reads; only A/B operand order differs.
// grid (64 n-tiles of 64, 2 och-halves of 160, 4 b) = 512 blocks, 256 thr.
__global__ __launch_bounds__(256) void qkv_mfma(
    const float* __restrict__ x, const __bf16* __restrict__ wbf,
    const float* __restrict__ bq, const float* __restrict__ bk,
    const float* __restrict__ bv,
    __bf16* __restrict__ qth, __bf16* __restrict__ qtl,
    __bf16* __restrict__ kth, __bf16* __restrict__ ktl,
    __bf16* __restrict__ vb)
{
    __shared__ __align__(16) __bf16 Wl[160][72];   // [och_local][c_chunk], 23 KB
    __shared__ __align__(16) __bf16 xT[64][72];    // [n_local][c_chunk], 9 KB
    __shared__ float bls[160];

    const int t = threadIdx.x, w = t >> 6, lane = t & 63;
    const int l31 = lane & 31, h = lane >> 5;
    const int b = blockIdx.z, hb = blockIdx.y, n0 = blockIdx.x * 64;

    if (t < 160) {
        int och = hb * 160 + t;
        bls[t] = och < 32 ? bq[och] : och < 64 ? bk[och - 32] : bv[och - 64];
    }

    // wave w owns local tiles j = w, w+4, w+8(<10); j -> (nt=j&1, otl=j>>1)
    f32x16 acc[3] = {zero16(), zero16(), zero16()};

    for (int kc = 0; kc < 4; ++kc) {           // K-chunks of 64 channels
        __syncthreads();
        #pragma unroll
        for (int i = 0; i < 5; ++i) {          // stage W chunk 160x64 bf16
            int e = t + 256 * i; int row = e >> 3, ch = e & 7;
            *(uint4*)&Wl[row][ch * 8] =
                *(const uint4*)(wbf + ((size_t)(hb * 160 + row)) * NI + kc * 64 + ch * 8);
        }
        #pragma unroll
        for (int i = 0; i < 4; ++i) {          // stage x chunk transposed 64n x 64c
            int e = t + 256 * i; int cc = e >> 4, jn = (e & 15) * 4;
            float4 xv = *(const float4*)(x + ((size_t)(b * NI) + kc * 64 + cc) * NPIX + n0 + jn);
            xT[jn    ][cc] = (__bf16)xv.x;
            xT[jn + 1][cc] = (__bf16)xv.y;
            xT[jn + 2][cc] = (__bf16)xv.z;
            xT[jn + 3][cc] = (__bf16)xv.w;
        }
        __syncthreads();

        #pragma unroll
        for (int kk = 0; kk < 4; ++kk) {
            bf16x8 xf0 = *(const bf16x8*)&xT[l31][kk * 16 + 8 * h];
            bf16x8 xf1 = *(const bf16x8*)&xT[32 + l31][kk * 16 + 8 * h];
            #pragma unroll
            for (int jj = 0; jj < 3; ++jj) {
                int j = w + 4 * jj;
                if (j < 10) {                  // wave-uniform branch
                    int nt = j & 1, otl = j >> 1;
                    bf16x8 wf = *(const bf16x8*)&Wl[otl * 32 + l31][kk * 16 + 8 * h];
                    bf16x8 xf = nt ? xf1 : xf0;
                    if (hb == 0 && otl < 2)    // q/k: C[n][och]
                        acc[jj] = __builtin_amdgcn_mfma_f32_32x32x16_bf16(xf, wf, acc[jj], 0, 0, 0);
                    else                       // v: C[och][n]
                        acc[jj] = __builtin_amdgcn_mfma_f32_32x32x16_bf16(wf, xf, acc[jj], 0, 0, 0);
                }
            }
        }
    }

    // epilogue
    #pragma unroll
    for (int jj = 0; jj < 3; ++jj) {
        int j = w + 4 * jj;
        if (j >= 10) continue;
        int nt = j & 1, otl = j >> 1;
        int gt = hb * 5 + otl;
        const f32x16& A = acc[jj];
        if (gt < 2) {                          // q or k -> hi/lo, [b][n][32]
            __bf16* dh = gt == 0 ? qth : kth;
            __bf16* dl = gt == 0 ? qtl : ktl;
            float bias = bls[otl * 32 + l31];
            #pragma unroll
            for (int r = 0; r < 16; ++r) {
                int rit = (r & 3) + 8 * (r >> 2) + 4 * h;
                int n = n0 + nt * 32 + rit;
                float val = A[r] + bias;
                __bf16 hh = (__bf16)val;
                size_t idx = ((size_t)b * NPIX + n) * QKC + l31;
                dh[idx] = hh;
                dl[idx] = (__bf16)(val - (float)hh);
            }
        } else {                               // v -> bf16 [b][c][n]
            #pragma unroll
            for (int r = 0; r < 16; ++r) {
                int rit = (r & 3) + 8 * (r >> 2) + 4 * h;
                int loc = otl * 32 + rit;
                int c = hb * 160 + loc - 64;
                float val = A[r] + bls[loc];
                vb[((size_t)(b * NI) + c) * NPIX + n0 + nt * 32 + l31] = (__bf16)val;
            }
        }
    }
}

// ---------------- Kernel 2: fused attention, 32 q-rows/block ----------------
// grid (128 q-tiles of 32, 4 b) = 512 blocks of 256 thr -> 2 blocks/CU.
// Waves 0,1: S quadrants (32x32 each over the 64-wide m-tile) + exp.
// All waves: PV over own 64-channel c-block; dens via ones-MFMA (ks==w).
__global__ __launch_bounds__(256) void attn_mfma(
    const float* __restrict__ x, const float* __restrict__ gamma,
    const __bf16* __restrict__ qth, const __bf16* __restrict__ qtl,
    const __bf16* __restrict__ kth, const __bf16* __restrict__ ktl,
    const __bf16* __restrict__ vb, float* __restrict__ out)
{
    __shared__ __align__(16) __bf16 vl[NI][72];     // 36864 B; reused as obuf f32[256][36]
    __shared__ __align__(16) __bf16 klh_s[64][40];  // 5120 B; head reused as dbuf f32[4][36]
    __shared__ __align__(16) __bf16 kll_s[64][40];  // 5120 B
    __shared__ __align__(16) __bf16 pt_s[32][72];   // 4608 B
    __shared__ float gls[NI];                       // 1024 B   (total ~52.7 KB)

    const int t = threadIdx.x;
    const int b = blockIdx.y;
    const int n0 = blockIdx.x * 32;
    const int w = t >> 6;
    const int lane = t & 63;
    const int l31 = lane & 31;
    const int h = lane >> 5;

    gls[t] = gamma[t];

    // q fragments: rows n0 + l31, k = 16*c + 8h + j (hi/lo)
    const size_t qrow = ((size_t)b * NPIX + n0 + l31) * QKC;
    bf16x8 qh0 = *(const bf16x8*)(qth + qrow + 8 * h);
    bf16x8 qh1 = *(const bf16x8*)(qth + qrow + 16 + 8 * h);
    bf16x8 ql0 = *(const bf16x8*)(qtl + qrow + 8 * h);
    bf16x8 ql1 = *(const bf16x8*)(qtl + qrow + 16 + 8 * h);

    bf16x8 ones;
    #pragma unroll
    for (int i = 0; i < 8; ++i) ones[i] = (__bf16)1.0f;

    f32x16 a0 = zero16(), a1 = zero16(), d = zero16();

    uint4 pv[8]; uint4 pkh, pkl;
    auto prefetch = [&](int m0) {
        #pragma unroll
        for (int i = 0; i < 8; ++i) {
            int e = t + 256 * i; int c = e >> 3, ch = e & 7;
            pv[i] = *(const uint4*)(vb + ((size_t)(b * NI + c)) * NPIX + m0 + ch * 8);
        }
        int m = t >> 2, ch = t & 3;
        pkh = *(const uint4*)(kth + ((size_t)b * NPIX + m0 + m) * QKC + ch * 8);
        pkl = *(const uint4*)(ktl + ((size_t)b * NPIX + m0 + m) * QKC + ch * 8);
    };
    prefetch(0);

    for (int mt = 0; mt < NPIX / 64; ++mt) {
        __syncthreads();                       // prior iter LDS reads done
        {
            int m = t >> 2, ch = t & 3;
            *(uint4*)&klh_s[m][ch * 8] = pkh;
            *(uint4*)&kll_s[m][ch * 8] = pkl;
        }
        #pragma unroll
        for (int i = 0; i < 8; ++i) {
            int e = t + 256 * i; int c = e >> 3, ch = e & 7;
            *(uint4*)&vl[c][ch * 8] = pv[i];
        }
        if (mt < NPIX / 64 - 1) prefetch((mt + 1) * 64);
        __syncthreads();                       // tiles staged

        if (w < 2) {                           // S quadrant (rows n0.., cols 32w..)
            f32x16 s1 = zero16(), s2 = zero16();
            bf16x8 kh0 = *(const bf16x8*)&klh_s[32 * w + l31][8 * h];
            bf16x8 kh1 = *(const bf16x8*)&klh_s[32 * w + l31][16 + 8 * h];
            bf16x8 kl0 = *(const bf16x8*)&kll_s[32 * w + l31][8 * h];
            bf16x8 kl1 = *(const bf16x8*)&kll_s[32 * w + l31][16 + 8 * h];
            s1 = __builtin_amdgcn_mfma_f32_32x32x16_bf16(qh0, kh0, s1, 0, 0, 0);
            s1 = __builtin_amdgcn_mfma_f32_32x32x16_bf16(qh1, kh1, s1, 0, 0, 0);
            s2 = __builtin_amdgcn_mfma_f32_32x32x16_bf16(ql0, kh0, s2, 0, 0, 0);
            s2 = __builtin_amdgcn_mfma_f32_32x32x16_bf16(ql1, kh1, s2, 0, 0, 0);
            s2 = __builtin_amdgcn_mfma_f32_32x32x16_bf16(qh0, kl0, s2, 0, 0, 0);
            s2 = __builtin_amdgcn_mfma_f32_32x32x16_bf16(qh1, kl1, s2, 0, 0, 0);
            #pragma unroll
            for (int r = 0; r < 16; ++r) {
                int rit = (r & 3) + 8 * (r >> 2) + 4 * h;
                pt_s[rit][32 * w + l31] = (__bf16)__expf(s1[r] + s2[r]);
            }
        }
        __syncthreads();                       // pt ready

        #pragma unroll
        for (int ks = 0; ks < 4; ++ks) {       // PV: c-block [64w, 64w+64)
            bf16x8 pa  = *(const bf16x8*)&pt_s[l31][ks * 16 + 8 * h];
            bf16x8 vb0 = *(const bf16x8*)&vl[64 * w + l31][ks * 16 + 8 * h];
            bf16x8 vb1 = *(const bf16x8*)&vl[64 * w + 32 + l31][ks * 16 + 8 * h];
            a0 = __builtin_amdgcn_mfma_f32_32x32x16_bf16(pa, vb0, a0, 0, 0, 0);
            a1 = __builtin_amdgcn_mfma_f32_32x32x16_bf16(pa, vb1, a1, 0, 0, 0);
            if (ks == w) d = __builtin_amdgcn_mfma_f32_32x32x16_bf16(pa, ones, d, 0, 0, 0);
        }
    }

    // ---- epilogue ----
    float (*dbuf)[36] = (float(*)[36])&klh_s[0][0];   // 576 B, over klh (not read in PV)
    if (l31 == 0) {
        #pragma unroll
        for (int r = 0; r < 16; ++r) {
            int rit = (r & 3) + 8 * (r >> 2) + 4 * h;
            dbuf[w][rit] = d[r];
        }
    }
    __syncthreads();
    float rd[16];
    #pragma unroll
    for (int r = 0; r < 16; ++r) {
        int rit = (r & 3) + 8 * (r >> 2) + 4 * h;
        rd[r] = 1.0f / (dbuf[0][rit] + dbuf[1][rit] + dbuf[2][rit] + dbuf[3][rit]);
    }

    float (*obuf)[36] = (float(*)[36])&vl[0][0];      // 256x36 f32 = 36864 B over vl
    #pragma unroll
    for (int u = 0; u < 2; ++u) {
        int c = 64 * w + 32 * u + l31;
        float g = gls[c];
        const f32x16& A = u ? a1 : a0;
        #pragma unroll
        for (int r = 0; r < 16; ++r) {
            int rit = (r & 3) + 8 * (r >> 2) + 4 * h;
            obuf[c][rit] = A[r] * rd[r] * g;
        }
    }
    __syncthreads();
    #pragma unroll
    for (int i = 0; i < 8; ++i) {
        int e = t + 256 * i; int c = e >> 3, nn4 = (e & 7) * 4;
        size_t base = ((size_t)(b * NI) + c) * NPIX + n0 + nn4;
        float4 o4 = *(const float4*)&obuf[c][nn4];
        float4 x4 = *(const float4*)&x[base];
        *(float4*)&out[base] = make_float4(o4.x + x4.x, o4.y + x4.y,
                                           o4.z + x4.z, o4.w + x4.w);
    }
}

extern "C" void kernel_launch(void* const* d_in, const int* in_sizes, int n_in,
                              void* d_out, int out_size, void* d_ws, size_t ws_size,
                              hipStream_t stream)
{
    const float* x     = (const float*)d_in[0];
    const float* wq    = (const float*)d_in[1];
    const float* bq    = (const float*)d_in[2];
    const float* wk    = (const float*)d_in[3];
    const float* bk    = (const float*)d_in[4];
    const float* wv    = (const float*)d_in[5];
    const float* bv    = (const float*)d_in[6];
    const float* gamma = (const float*)d_in[7];
    float* out = (float*)d_out;

    // ws: wbf[320*256] | qth|qtl|kth|ktl [4][4096][32] | vb [4][256][4096]  (~12.75 MB bf16)
    const size_t WSZ = (size_t)320 * NI;
    const size_t QSZ = (size_t)BS * NPIX * QKC;
    __bf16* wbf = (__bf16*)d_ws;
    __bf16* qth = wbf + WSZ;
    __bf16* qtl = qth + QSZ;
    __bf16* kth = qtl + QSZ;
    __bf16* ktl = kth + QSZ;
    __bf16* vb  = ktl + QSZ;

    wconv<<<dim3(80), 256, 0, stream>>>(wq, wk, wv, wbf);
    qkv_mfma<<<dim3(64, 2, BS), 256, 0, stream>>>(x, wbf, bq, bk, bv,
                                                  qth, qtl, kth, ktl, vb);
    attn_mfma<<<dim3(NPIX / 32, BS), 256, 0, stream>>>(x, gamma, qth, qtl, kth, ktl, vb, out);
}

// Round 5
// 290.978 us; speedup vs baseline: 1.6889x; 1.6889x over previous
//
#include <hip/hip_runtime.h>
#include <cstdint>
#include <cstddef>

#define NI   256
#define QKC  32
#define BS   4
#define NPIX 4096   // 64*64

typedef __bf16 bf16x8 __attribute__((ext_vector_type(8)));
typedef __bf16 bf16x4 __attribute__((ext_vector_type(4)));
typedef float  f32x16 __attribute__((ext_vector_type(16)));

__device__ inline f32x16 zero16() {
    f32x16 z;
    #pragma unroll
    for (int i = 0; i < 16; ++i) z[i] = 0.f;
    return z;
}

// ---------------- Kernel 0: W fp32 -> bf16, concat [320][256] ----------------
__global__ __launch_bounds__(256) void wconv(
    const float* __restrict__ wq, const float* __restrict__ wk,
    const float* __restrict__ wv, __bf16* __restrict__ wbf)
{
    int f = (blockIdx.x * 256 + threadIdx.x) * 4;
    int row = f >> 8, c = f & 255;
    const float* src = row < 32 ? wq + row * NI + c
                     : row < 64 ? wk + (row - 32) * NI + c
                                : wv + (row - 64) * NI + c;
    float4 v = *(const float4*)src;
    __align__(8) __bf16 o4[4] = {(__bf16)v.x, (__bf16)v.y, (__bf16)v.z, (__bf16)v.w};
    *(uint2*)(wbf + f) = *(const uint2*)o4;
}

// ---------------- Kernel 1: QKV projection as bf16 MFMA GEMM ----------------
// out[320][4096] = W[320][256] x x[256][4096] per batch.
// q,k: C[n][och] -> hi/lo split [b][n][32]; v: C[och][n] -> bf16 [b][c][n].
// grid (64 n-tiles, 2 och-halves of 160, 4 b), 256 thr.
__global__ __launch_bounds__(256) void qkv_mfma(
    const float* __restrict__ x, const __bf16* __restrict__ wbf,
    const float* __restrict__ bq, const float* __restrict__ bk,
    const float* __restrict__ bv,
    __bf16* __restrict__ qth, __bf16* __restrict__ qtl,
    __bf16* __restrict__ kth, __bf16* __restrict__ ktl,
    __bf16* __restrict__ vb)
{
    __shared__ __align__(16) __bf16 Wl[160][72];
    __shared__ __align__(16) __bf16 xT[64][72];
    __shared__ float bls[160];

    const int t = threadIdx.x, w = t >> 6, lane = t & 63;
    const int l31 = lane & 31, h = lane >> 5;
    const int b = blockIdx.z, hb = blockIdx.y, n0 = blockIdx.x * 64;

    if (t < 160) {
        int och = hb * 160 + t;
        bls[t] = och < 32 ? bq[och] : och < 64 ? bk[och - 32] : bv[och - 64];
    }

    f32x16 acc[3] = {zero16(), zero16(), zero16()};

    for (int kc = 0; kc < 4; ++kc) {
        __syncthreads();
        #pragma unroll
        for (int i = 0; i < 5; ++i) {          // stage W chunk 160x64
            int e = t + 256 * i; int row = e >> 3, ch = e & 7;
            *(uint4*)&Wl[row][ch * 8] =
                *(const uint4*)(wbf + ((size_t)(hb * 160 + row)) * NI + kc * 64 + ch * 8);
        }
        {   // stage x chunk transposed 64n x 64c via 4x4 micro-tiles (b64 writes)
            int n4 = (t & 15) * 4, c4 = (t >> 4) * 4;
            float4 xv[4];
            #pragma unroll
            for (int j = 0; j < 4; ++j)
                xv[j] = *(const float4*)(x + ((size_t)(b * NI) + kc * 64 + c4 + j) * NPIX + n0 + n4);
            #pragma unroll
            for (int i = 0; i < 4; ++i) {
                __align__(8) __bf16 r4[4] = {
                    (__bf16)((&xv[0].x)[i]), (__bf16)((&xv[1].x)[i]),
                    (__bf16)((&xv[2].x)[i]), (__bf16)((&xv[3].x)[i])};
                *(uint2*)&xT[n4 + i][c4] = *(const uint2*)r4;
            }
        }
        __syncthreads();

        #pragma unroll
        for (int kk = 0; kk < 4; ++kk) {
            bf16x8 xf0 = *(const bf16x8*)&xT[l31][kk * 16 + 8 * h];
            bf16x8 xf1 = *(const bf16x8*)&xT[32 + l31][kk * 16 + 8 * h];
            #pragma unroll
            for (int jj = 0; jj < 3; ++jj) {
                int j = w + 4 * jj;
                if (j < 10) {                  // wave-uniform
                    int nt = j & 1, otl = j >> 1;
                    bf16x8 wf = *(const bf16x8*)&Wl[otl * 32 + l31][kk * 16 + 8 * h];
                    bf16x8 xf = nt ? xf1 : xf0;
                    if (hb == 0 && otl < 2)
                        acc[jj] = __builtin_amdgcn_mfma_f32_32x32x16_bf16(xf, wf, acc[jj], 0, 0, 0);
                    else
                        acc[jj] = __builtin_amdgcn_mfma_f32_32x32x16_bf16(wf, xf, acc[jj], 0, 0, 0);
                }
            }
        }
    }

    #pragma unroll
    for (int jj = 0; jj < 3; ++jj) {
        int j = w + 4 * jj;
        if (j >= 10) continue;
        int nt = j & 1, otl = j >> 1;
        int gt = hb * 5 + otl;
        const f32x16& A = acc[jj];
        if (gt < 2) {                          // q or k -> hi/lo [b][n][32]
            __bf16* dh = gt == 0 ? qth : kth;
            __bf16* dl = gt == 0 ? qtl : ktl;
            float bias = bls[otl * 32 + l31];
            #pragma unroll
            for (int r = 0; r < 16; ++r) {
                int rit = (r & 3) + 8 * (r >> 2) + 4 * h;
                int n = n0 + nt * 32 + rit;
                float val = A[r] + bias;
                __bf16 hh = (__bf16)val;
                size_t idx = ((size_t)b * NPIX + n) * QKC + l31;
                dh[idx] = hh;
                dl[idx] = (__bf16)(val - (float)hh);
            }
        } else {                               // v -> bf16 [b][c][n]
            #pragma unroll
            for (int r = 0; r < 16; ++r) {
                int rit = (r & 3) + 8 * (r >> 2) + 4 * h;
                int loc = otl * 32 + rit;
                int c = hb * 160 + loc - 64;
                float val = A[r] + bls[loc];
                vb[((size_t)(b * NI) + c) * NPIX + n0 + nt * 32 + l31] = (__bf16)val;
            }
        }
    }
}

// ---------------- Kernel 2: attention, 64 q-rows/block, k-split x2 ----------------
// grid (64 n-tiles, 2 k-halves, 4 b) = 512 blocks of 256 thr -> 2 blocks/CU.
// Each block processes 2048 keys; writes UNNORMALIZED O-partial (bf16,
// [split][b][c][n]) and fp32 denom partial [split][b][n]. Exact combine later
// (no max-subtraction softmax -> partials add).
__global__ __launch_bounds__(256) void attn_mfma(
    const __bf16* __restrict__ qth, const __bf16* __restrict__ qtl,
    const __bf16* __restrict__ kth, const __bf16* __restrict__ ktl,
    const __bf16* __restrict__ vb,
    __bf16* __restrict__ Opart, float* __restrict__ dpart)
{
    __shared__ __align__(16) __bf16 vl[NI][72];     // 36864 B; reused as obuf bf16[256][72]
    __shared__ __align__(16) __bf16 klh_s[64][40];  // 5120 B
    __shared__ __align__(16) __bf16 kll_s[64][40];  // 5120 B
    __shared__ __align__(16) __bf16 pt_s[64][72];   // 9216 B   (total ~55 KB)

    const int t    = threadIdx.x;
    const int b    = blockIdx.z;
    const int ksp  = blockIdx.y;                    // key-split half
    const int n0   = blockIdx.x * 64;
    const int w    = t >> 6;
    const int lane = t & 63;
    const int l31  = lane & 31;
    const int h    = lane >> 5;
    const int sr   = w & 1, sc = w >> 1;
    const int mbase = ksp * (NPIX / 2);

    const size_t qrow = ((size_t)b * NPIX + n0 + 32 * sr + l31) * QKC;
    bf16x8 qh0 = *(const bf16x8*)(qth + qrow + 8 * h);
    bf16x8 qh1 = *(const bf16x8*)(qth + qrow + 16 + 8 * h);
    bf16x8 ql0 = *(const bf16x8*)(qtl + qrow + 8 * h);
    bf16x8 ql1 = *(const bf16x8*)(qtl + qrow + 16 + 8 * h);

    bf16x8 ones;
    #pragma unroll
    for (int i = 0; i < 8; ++i) ones[i] = (__bf16)1.0f;

    f32x16 a00 = zero16(), a01 = zero16(), a10 = zero16(), a11 = zero16();
    f32x16 d0 = zero16(), d1 = zero16();

    uint4 pv[8]; uint4 pkh, pkl;
    const int vm = t >> 2, vch = t & 3;
    auto prefetch = [&](int m0) {
        #pragma unroll
        for (int i = 0; i < 8; ++i) {
            int e = t + 256 * i; int c = e >> 3, ch = e & 7;
            pv[i] = *(const uint4*)(vb + ((size_t)(b * NI + c)) * NPIX + m0 + ch * 8);
        }
        pkh = *(const uint4*)(kth + ((size_t)b * NPIX + m0 + vm) * QKC + vch * 8);
        pkl = *(const uint4*)(ktl + ((size_t)b * NPIX + m0 + vm) * QKC + vch * 8);
    };
    prefetch(mbase);

    for (int mt = 0; mt < NPIX / 2 / 64; ++mt) {
        __syncthreads();
        *(uint4*)&klh_s[vm][vch * 8] = pkh;
        *(uint4*)&kll_s[vm][vch * 8] = pkl;
        #pragma unroll
        for (int i = 0; i < 8; ++i) {
            int e = t + 256 * i; int c = e >> 3, ch = e & 7;
            *(uint4*)&vl[c][ch * 8] = pv[i];
        }
        if (mt < NPIX / 2 / 64 - 1) prefetch(mbase + (mt + 1) * 64);
        __syncthreads();

        // ---- S quadrant (rows 32*sr.., cols 32*sc..), hi/lo 3-term ----
        f32x16 s = zero16();
        bf16x8 kh0  = *(const bf16x8*)&klh_s[sc * 32 + l31][8 * h];
        bf16x8 kh1  = *(const bf16x8*)&klh_s[sc * 32 + l31][16 + 8 * h];
        bf16x8 klo0 = *(const bf16x8*)&kll_s[sc * 32 + l31][8 * h];
        bf16x8 klo1 = *(const bf16x8*)&kll_s[sc * 32 + l31][16 + 8 * h];
        s = __builtin_amdgcn_mfma_f32_32x32x16_bf16(qh0, kh0, s, 0, 0, 0);
        s = __builtin_amdgcn_mfma_f32_32x32x16_bf16(qh1, kh1, s, 0, 0, 0);
        s = __builtin_amdgcn_mfma_f32_32x32x16_bf16(ql0, kh0, s, 0, 0, 0);
        s = __builtin_amdgcn_mfma_f32_32x32x16_bf16(ql1, kh1, s, 0, 0, 0);
        s = __builtin_amdgcn_mfma_f32_32x32x16_bf16(qh0, klo0, s, 0, 0, 0);
        s = __builtin_amdgcn_mfma_f32_32x32x16_bf16(qh1, klo1, s, 0, 0, 0);

        #pragma unroll
        for (int r = 0; r < 16; ++r) {
            int rit = (r & 3) + 8 * (r >> 2) + 4 * h;
            pt_s[32 * sr + rit][32 * sc + l31] = (__bf16)__expf(s[r]);
        }
        __syncthreads();

        // ---- PV + denom over full 64-wide tile ----
        #pragma unroll
        for (int ks = 0; ks < 4; ++ks) {
            bf16x8 pa0 = *(const bf16x8*)&pt_s[l31][ks * 16 + 8 * h];
            bf16x8 pa1 = *(const bf16x8*)&pt_s[32 + l31][ks * 16 + 8 * h];
            d0 = __builtin_amdgcn_mfma_f32_32x32x16_bf16(pa0, ones, d0, 0, 0, 0);
            d1 = __builtin_amdgcn_mfma_f32_32x32x16_bf16(pa1, ones, d1, 0, 0, 0);
            bf16x8 vb0 = *(const bf16x8*)&vl[(2 * w) * 32 + l31][ks * 16 + 8 * h];
            bf16x8 vb1 = *(const bf16x8*)&vl[(2 * w + 1) * 32 + l31][ks * 16 + 8 * h];
            a00 = __builtin_amdgcn_mfma_f32_32x32x16_bf16(pa0, vb0, a00, 0, 0, 0);
            a10 = __builtin_amdgcn_mfma_f32_32x32x16_bf16(pa1, vb0, a10, 0, 0, 0);
            a01 = __builtin_amdgcn_mfma_f32_32x32x16_bf16(pa0, vb1, a01, 0, 0, 0);
            a11 = __builtin_amdgcn_mfma_f32_32x32x16_bf16(pa1, vb1, a11, 0, 0, 0);
        }
    }

    // ---- epilogue: write denom partial + unnormalized O partial (bf16) ----
    if (w == 0 && l31 == 0) {   // d replicated across cols & waves; rows via (h, r)
        size_t dbase = ((size_t)(ksp * BS + b)) * NPIX + n0;
        #pragma unroll
        for (int r = 0; r < 16; ++r) {
            int rit = (r & 3) + 8 * (r >> 2) + 4 * h;
            dpart[dbase + rit]      = d0[r];
            dpart[dbase + 32 + rit] = d1[r];
        }
    }
    __syncthreads();   // vl reads (PV) done before overwrite as obuf

    __bf16 (*obuf)[72] = (__bf16(*)[72])&vl[0][0];   // [c][n] bf16
    #pragma unroll
    for (int ctl = 0; ctl < 2; ++ctl) {
        int c = (2 * w + ctl) * 32 + l31;
        const f32x16& A0 = ctl ? a01 : a00;
        const f32x16& A1 = ctl ? a11 : a10;
        #pragma unroll
        for (int r = 0; r < 16; ++r) {
            int rit = (r & 3) + 8 * (r >> 2) + 4 * h;
            obuf[c][rit]      = (__bf16)A0[r];
            obuf[c][32 + rit] = (__bf16)A1[r];
        }
    }
    __syncthreads();
    #pragma unroll
    for (int i = 0; i < 16; ++i) {
        int e = t + 256 * i; int c = e >> 4, nn4 = (e & 15) * 4;
        size_t base = (((size_t)(ksp * BS + b)) * NI + c) * NPIX + n0 + nn4;
        *(uint2*)&Opart[base] = *(const uint2*)&obuf[c][nn4];
    }
}

// ---------------- Kernel 3: combine ----------------
// out[b][c][n] = gamma[c] * (O0+O1)[c][n] / (d0+d1)[n] + x
__global__ __launch_bounds__(256) void combine(
    const float* __restrict__ x, const float* __restrict__ gamma,
    const __bf16* __restrict__ Opart, const float* __restrict__ dpart,
    float* __restrict__ out)
{
    int idx = (blockIdx.x * 256 + threadIdx.x) * 4;
    int n = idx & (NPIX - 1);
    int c = (idx >> 12) & (NI - 1);
    int b = idx >> 20;

    size_t o0 = (((size_t)(0 * BS + b)) * NI + c) * NPIX + n;
    size_t o1 = (((size_t)(1 * BS + b)) * NI + c) * NPIX + n;
    bf16x4 p0 = *(const bf16x4*)(Opart + o0);
    bf16x4 p1 = *(const bf16x4*)(Opart + o1);
    float4 da = *(const float4*)(dpart + ((size_t)(0 * BS + b)) * NPIX + n);
    float4 db = *(const float4*)(dpart + ((size_t)(1 * BS + b)) * NPIX + n);
    size_t xb = ((size_t)(b * NI) + c) * NPIX + n;
    float4 xv = *(const float4*)(x + xb);
    float g = gamma[c];

    float4 r;
    r.x = g * (((float)p0[0] + (float)p1[0]) / (da.x + db.x)) + xv.x;
    r.y = g * (((float)p0[1] + (float)p1[1]) / (da.y + db.y)) + xv.y;
    r.z = g * (((float)p0[2] + (float)p1[2]) / (da.z + db.z)) + xv.z;
    r.w = g * (((float)p0[3] + (float)p1[3]) / (da.w + db.w)) + xv.w;
    *(float4*)(out + xb) = r;
}

extern "C" void kernel_launch(void* const* d_in, const int* in_sizes, int n_in,
                              void* d_out, int out_size, void* d_ws, size_t ws_size,
                              hipStream_t stream)
{
    const float* x     = (const float*)d_in[0];
    const float* wq    = (const float*)d_in[1];
    const float* bq    = (const float*)d_in[2];
    const float* wk    = (const float*)d_in[3];
    const float* bk    = (const float*)d_in[4];
    const float* wv    = (const float*)d_in[5];
    const float* bv    = (const float*)d_in[6];
    const float* gamma = (const float*)d_in[7];
    float* out = (float*)d_out;

    // ws: wbf | qth|qtl|kth|ktl | vb | Opart bf16 [2][4][256][4096] | dpart f32 [2][4][4096]
    const size_t WSZ = (size_t)320 * NI;
    const size_t QSZ = (size_t)BS * NPIX * QKC;
    const size_t VSZ = (size_t)BS * NI * NPIX;
    __bf16* wbf   = (__bf16*)d_ws;
    __bf16* qth   = wbf + WSZ;
    __bf16* qtl   = qth + QSZ;
    __bf16* kth   = qtl + QSZ;
    __bf16* ktl   = kth + QSZ;
    __bf16* vb    = ktl + QSZ;
    __bf16* Opart = vb + VSZ;
    float*  dpart = (float*)(Opart + 2 * VSZ);

    wconv<<<dim3(80), 256, 0, stream>>>(wq, wk, wv, wbf);
    qkv_mfma<<<dim3(64, 2, BS), 256, 0, stream>>>(x, wbf, bq, bk, bv,
                                                  qth, qtl, kth, ktl, vb);
    attn_mfma<<<dim3(64, 2, BS), 256, 0, stream>>>(qth, qtl, kth, ktl, vb, Opart, dpart);
    combine<<<dim3(BS * NI * NPIX / 1024), 256, 0, stream>>>(x, gamma, Opart, dpart, out);
}

// Round 6
// 273.203 us; speedup vs baseline: 1.7988x; 1.0651x over previous
//
#include <hip/hip_runtime.h>
#include <cstdint>
#include <cstddef>

#define NI   256
#define QKC  32
#define BS   4
#define NPIX 4096   // 64*64

typedef __bf16 bf16x8 __attribute__((ext_vector_type(8)));
typedef __bf16 bf16x4 __attribute__((ext_vector_type(4)));
typedef float  f32x16 __attribute__((ext_vector_type(16)));

__device__ inline f32x16 zero16() {
    f32x16 z;
    #pragma unroll
    for (int i = 0; i < 16; ++i) z[i] = 0.f;
    return z;
}

// ---------------- Kernel 0: W fp32 -> bf16, concat [320][256] ----------------
__global__ __launch_bounds__(256) void wconv(
    const float* __restrict__ wq, const float* __restrict__ wk,
    const float* __restrict__ wv, __bf16* __restrict__ wbf)
{
    int f = (blockIdx.x * 256 + threadIdx.x) * 4;
    int row = f >> 8, c = f & 255;
    const float* src = row < 32 ? wq + row * NI + c
                     : row < 64 ? wk + (row - 32) * NI + c
                                : wv + (row - 64) * NI + c;
    float4 v = *(const float4*)src;
    __align__(8) __bf16 o4[4] = {(__bf16)v.x, (__bf16)v.y, (__bf16)v.z, (__bf16)v.w};
    *(uint2*)(wbf + f) = *(const uint2*)o4;
}

// ---------------- Kernel 1: QKV projection as bf16 MFMA GEMM ----------------
// q: hi/lo split [b][n][32]; k: hi only [b][n][32]; v: bf16 [b][c][n].
__global__ __launch_bounds__(256) void qkv_mfma(
    const float* __restrict__ x, const __bf16* __restrict__ wbf,
    const float* __restrict__ bq, const float* __restrict__ bk,
    const float* __restrict__ bv,
    __bf16* __restrict__ qth, __bf16* __restrict__ qtl,
    __bf16* __restrict__ kth, __bf16* __restrict__ vb)
{
    __shared__ __align__(16) __bf16 Wl[160][72];
    __shared__ __align__(16) __bf16 xT[64][72];
    __shared__ float bls[160];

    const int t = threadIdx.x, w = t >> 6, lane = t & 63;
    const int l31 = lane & 31, h = lane >> 5;
    const int b = blockIdx.z, hb = blockIdx.y, n0 = blockIdx.x * 64;

    if (t < 160) {
        int och = hb * 160 + t;
        bls[t] = och < 32 ? bq[och] : och < 64 ? bk[och - 32] : bv[och - 64];
    }

    f32x16 acc[3] = {zero16(), zero16(), zero16()};

    for (int kc = 0; kc < 4; ++kc) {
        __syncthreads();
        #pragma unroll
        for (int i = 0; i < 5; ++i) {          // stage W chunk 160x64
            int e = t + 256 * i; int row = e >> 3, ch = e & 7;
            *(uint4*)&Wl[row][ch * 8] =
                *(const uint4*)(wbf + ((size_t)(hb * 160 + row)) * NI + kc * 64 + ch * 8);
        }
        {   // stage x chunk transposed 64n x 64c via 4x4 micro-tiles
            int n4 = (t & 15) * 4, c4 = (t >> 4) * 4;
            float4 xv[4];
            #pragma unroll
            for (int j = 0; j < 4; ++j)
                xv[j] = *(const float4*)(x + ((size_t)(b * NI) + kc * 64 + c4 + j) * NPIX + n0 + n4);
            #pragma unroll
            for (int i = 0; i < 4; ++i) {
                __align__(8) __bf16 r4[4] = {
                    (__bf16)((&xv[0].x)[i]), (__bf16)((&xv[1].x)[i]),
                    (__bf16)((&xv[2].x)[i]), (__bf16)((&xv[3].x)[i])};
                *(uint2*)&xT[n4 + i][c4] = *(const uint2*)r4;
            }
        }
        __syncthreads();

        #pragma unroll
        for (int kk = 0; kk < 4; ++kk) {
            bf16x8 xf0 = *(const bf16x8*)&xT[l31][kk * 16 + 8 * h];
            bf16x8 xf1 = *(const bf16x8*)&xT[32 + l31][kk * 16 + 8 * h];
            #pragma unroll
            for (int jj = 0; jj < 3; ++jj) {
                int j = w + 4 * jj;
                if (j < 10) {                  // wave-uniform
                    int nt = j & 1, otl = j >> 1;
                    bf16x8 wf = *(const bf16x8*)&Wl[otl * 32 + l31][kk * 16 + 8 * h];
                    bf16x8 xf = nt ? xf1 : xf0;
                    if (hb == 0 && otl < 2)
                        acc[jj] = __builtin_amdgcn_mfma_f32_32x32x16_bf16(xf, wf, acc[jj], 0, 0, 0);
                    else
                        acc[jj] = __builtin_amdgcn_mfma_f32_32x32x16_bf16(wf, xf, acc[jj], 0, 0, 0);
                }
            }
        }
    }

    #pragma unroll
    for (int jj = 0; jj < 3; ++jj) {
        int j = w + 4 * jj;
        if (j >= 10) continue;
        int nt = j & 1, otl = j >> 1;
        int gt = hb * 5 + otl;
        const f32x16& A = acc[jj];
        if (gt < 2) {                          // q (hi+lo) or k (hi only), [b][n][32]
            __bf16* dh = gt == 0 ? qth : kth;
            float bias = bls[otl * 32 + l31];
            #pragma unroll
            for (int r = 0; r < 16; ++r) {
                int rit = (r & 3) + 8 * (r >> 2) + 4 * h;
                int n = n0 + nt * 32 + rit;
                float val = A[r] + bias;
                __bf16 hh = (__bf16)val;
                size_t idx = ((size_t)b * NPIX + n) * QKC + l31;
                dh[idx] = hh;
                if (gt == 0) qtl[idx] = (__bf16)(val - (float)hh);
            }
        } else {                               // v -> bf16 [b][c][n]
            #pragma unroll
            for (int r = 0; r < 16; ++r) {
                int rit = (r & 3) + 8 * (r >> 2) + 4 * h;
                int loc = otl * 32 + rit;
                int c = hb * 160 + loc - 64;
                float val = A[r] + bls[loc];
                vb[((size_t)(b * NI) + c) * NPIX + n0 + nt * 32 + l31] = (__bf16)val;
            }
        }
    }
}

// ---------------- Kernel 2: attention, 64 q-rows/block, k-split x2 ----------------
// grid (64 n-tiles, 2 k-halves, 4 b) = 512 blocks of 256 thr.
// Register budget trimmed (no K-lo, single d accumulator) for 2 waves/SIMD ->
// 2 blocks/CU. Prefetch issued AFTER the pt-barrier so the loop-top vmcnt
// drain has the whole PV phase as slack.
__global__ __launch_bounds__(256) void attn_mfma(
    const __bf16* __restrict__ qth, const __bf16* __restrict__ qtl,
    const __bf16* __restrict__ kth, const __bf16* __restrict__ vb,
    __bf16* __restrict__ Opart, float* __restrict__ dpart)
{
    __shared__ __align__(16) __bf16 vl[NI][72];     // 36864 B; reused as obuf bf16[256][72]
    __shared__ __align__(16) __bf16 klh_s[64][40];  // 5120 B; reused as dbuf f32[4][36]
    __shared__ __align__(16) __bf16 pt_s[64][72];   // 9216 B   (total 51200 B)

    const int t    = threadIdx.x;
    const int b    = blockIdx.z;
    const int ksp  = blockIdx.y;
    const int n0   = blockIdx.x * 64;
    const int w    = t >> 6;
    const int lane = t & 63;
    const int l31  = lane & 31;
    const int h    = lane >> 5;
    const int sr   = w & 1, sc = w >> 1;
    const int mbase = ksp * (NPIX / 2);

    const size_t qrow = ((size_t)b * NPIX + n0 + 32 * sr + l31) * QKC;
    bf16x8 qh0 = *(const bf16x8*)(qth + qrow + 8 * h);
    bf16x8 qh1 = *(const bf16x8*)(qth + qrow + 16 + 8 * h);
    bf16x8 ql0 = *(const bf16x8*)(qtl + qrow + 8 * h);
    bf16x8 ql1 = *(const bf16x8*)(qtl + qrow + 16 + 8 * h);

    bf16x8 ones;
    #pragma unroll
    for (int i = 0; i < 8; ++i) ones[i] = (__bf16)1.0f;

    f32x16 a00 = zero16(), a01 = zero16(), a10 = zero16(), a11 = zero16();
    f32x16 d = zero16();   // this wave: rows 32*sr.., key-cols 32*sc.. partial

    uint4 pv[8]; uint4 pkh;
    const int vm = t >> 2, vch = t & 3;
    auto prefetch = [&](int m0) {
        #pragma unroll
        for (int i = 0; i < 8; ++i) {
            int e = t + 256 * i; int c = e >> 3, ch = e & 7;
            pv[i] = *(const uint4*)(vb + ((size_t)(b * NI + c)) * NPIX + m0 + ch * 8);
        }
        pkh = *(const uint4*)(kth + ((size_t)b * NPIX + m0 + vm) * QKC + vch * 8);
    };
    prefetch(mbase);

    const int NIT = NPIX / 2 / 64;
    for (int mt = 0; mt < NIT; ++mt) {
        __syncthreads();                       // (A) prior LDS reads done; drains prefetch
        *(uint4*)&klh_s[vm][vch * 8] = pkh;
        #pragma unroll
        for (int i = 0; i < 8; ++i) {
            int e = t + 256 * i; int c = e >> 3, ch = e & 7;
            *(uint4*)&vl[c][ch * 8] = pv[i];
        }
        __syncthreads();                       // (B) tiles staged

        // ---- S quadrant: (qh+ql) x k_bf16, 4 MFMA ----
        f32x16 s = zero16();
        bf16x8 kh0 = *(const bf16x8*)&klh_s[sc * 32 + l31][8 * h];
        bf16x8 kh1 = *(const bf16x8*)&klh_s[sc * 32 + l31][16 + 8 * h];
        s = __builtin_amdgcn_mfma_f32_32x32x16_bf16(qh0, kh0, s, 0, 0, 0);
        s = __builtin_amdgcn_mfma_f32_32x32x16_bf16(qh1, kh1, s, 0, 0, 0);
        s = __builtin_amdgcn_mfma_f32_32x32x16_bf16(ql0, kh0, s, 0, 0, 0);
        s = __builtin_amdgcn_mfma_f32_32x32x16_bf16(ql1, kh1, s, 0, 0, 0);

        #pragma unroll
        for (int r = 0; r < 16; ++r) {
            int rit = (r & 3) + 8 * (r >> 2) + 4 * h;
            pt_s[32 * sr + rit][32 * sc + l31] = (__bf16)__expf(s[r]);
        }
        __syncthreads();                       // (C) pt ready

        if (mt < NIT - 1) prefetch(mbase + (mt + 1) * 64);   // overlap with PV

        #pragma unroll
        for (int ks = 0; ks < 4; ++ks) {
            bf16x8 pa0 = *(const bf16x8*)&pt_s[l31][ks * 16 + 8 * h];
            bf16x8 pa1 = *(const bf16x8*)&pt_s[32 + l31][ks * 16 + 8 * h];
            if ((ks >> 1) == sc)               // this wave's col-half, own row-half
                d = __builtin_amdgcn_mfma_f32_32x32x16_bf16(sr ? pa1 : pa0, ones, d, 0, 0, 0);
            bf16x8 vb0 = *(const bf16x8*)&vl[(2 * w) * 32 + l31][ks * 16 + 8 * h];
            bf16x8 vb1 = *(const bf16x8*)&vl[(2 * w + 1) * 32 + l31][ks * 16 + 8 * h];
            a00 = __builtin_amdgcn_mfma_f32_32x32x16_bf16(pa0, vb0, a00, 0, 0, 0);
            a10 = __builtin_amdgcn_mfma_f32_32x32x16_bf16(pa1, vb0, a10, 0, 0, 0);
            a01 = __builtin_amdgcn_mfma_f32_32x32x16_bf16(pa0, vb1, a01, 0, 0, 0);
            a11 = __builtin_amdgcn_mfma_f32_32x32x16_bf16(pa1, vb1, a11, 0, 0, 0);
        }
    }

    // ---- epilogue: combine d partials, write dpart + unnormalized O ----
    float (*dbuf)[36] = (float(*)[36])&klh_s[0][0];
    if (l31 == 0) {
        #pragma unroll
        for (int r = 0; r < 16; ++r) {
            int rit = (r & 3) + 8 * (r >> 2) + 4 * h;
            dbuf[w][rit] = d[r];
        }
    }
    __syncthreads();   // all waves past PV; dbuf complete
    if (w < 2 && l31 == 0) {
        // rows 32w+rit: waves {w, w+2} cover the two key-col halves
        size_t dbase = ((size_t)(ksp * BS + b)) * NPIX + n0 + 32 * w;
        #pragma unroll
        for (int r = 0; r < 16; ++r) {
            int rit = (r & 3) + 8 * (r >> 2) + 4 * h;
            dpart[dbase + rit] = dbuf[w][rit] + dbuf[w + 2][rit];
        }
    }

    __bf16 (*obuf)[72] = (__bf16(*)[72])&vl[0][0];
    #pragma unroll
    for (int ctl = 0; ctl < 2; ++ctl) {
        int c = (2 * w + ctl) * 32 + l31;
        const f32x16& A0 = ctl ? a01 : a00;
        const f32x16& A1 = ctl ? a11 : a10;
        #pragma unroll
        for (int r = 0; r < 16; ++r) {
            int rit = (r & 3) + 8 * (r >> 2) + 4 * h;
            obuf[c][rit]      = (__bf16)A0[r];
            obuf[c][32 + rit] = (__bf16)A1[r];
        }
    }
    __syncthreads();
    #pragma unroll
    for (int i = 0; i < 16; ++i) {
        int e = t + 256 * i; int c = e >> 4, nn4 = (e & 15) * 4;
        size_t base = (((size_t)(ksp * BS + b)) * NI + c) * NPIX + n0 + nn4;
        *(uint2*)&Opart[base] = *(const uint2*)&obuf[c][nn4];
    }
}

// ---------------- Kernel 3: combine ----------------
__global__ __launch_bounds__(256) void combine(
    const float* __restrict__ x, const float* __restrict__ gamma,
    const __bf16* __restrict__ Opart, const float* __restrict__ dpart,
    float* __restrict__ out)
{
    int idx = (blockIdx.x * 256 + threadIdx.x) * 4;
    int n = idx & (NPIX - 1);
    int c = (idx >> 12) & (NI - 1);
    int b = idx >> 20;

    size_t o0 = (((size_t)(0 * BS + b)) * NI + c) * NPIX + n;
    size_t o1 = (((size_t)(1 * BS + b)) * NI + c) * NPIX + n;
    bf16x4 p0 = *(const bf16x4*)(Opart + o0);
    bf16x4 p1 = *(const bf16x4*)(Opart + o1);
    float4 da = *(const float4*)(dpart + ((size_t)(0 * BS + b)) * NPIX + n);
    float4 db = *(const float4*)(dpart + ((size_t)(1 * BS + b)) * NPIX + n);
    size_t xb = ((size_t)(b * NI) + c) * NPIX + n;
    float4 xv = *(const float4*)(x + xb);
    float g = gamma[c];

    float4 r;
    r.x = g * (((float)p0[0] + (float)p1[0]) / (da.x + db.x)) + xv.x;
    r.y = g * (((float)p0[1] + (float)p1[1]) / (da.y + db.y)) + xv.y;
    r.z = g * (((float)p0[2] + (float)p1[2]) / (da.z + db.z)) + xv.z;
    r.w = g * (((float)p0[3] + (float)p1[3]) / (da.w + db.w)) + xv.w;
    *(float4*)(out + xb) = r;
}

extern "C" void kernel_launch(void* const* d_in, const int* in_sizes, int n_in,
                              void* d_out, int out_size, void* d_ws, size_t ws_size,
                              hipStream_t stream)
{
    const float* x     = (const float*)d_in[0];
    const float* wq    = (const float*)d_in[1];
    const float* bq    = (const float*)d_in[2];
    const float* wk    = (const float*)d_in[3];
    const float* bk    = (const float*)d_in[4];
    const float* wv    = (const float*)d_in[5];
    const float* bv    = (const float*)d_in[6];
    const float* gamma = (const float*)d_in[7];
    float* out = (float*)d_out;

    const size_t WSZ = (size_t)320 * NI;
    const size_t QSZ = (size_t)BS * NPIX * QKC;
    const size_t VSZ = (size_t)BS * NI * NPIX;
    __bf16* wbf   = (__bf16*)d_ws;
    __bf16* qth   = wbf + WSZ;
    __bf16* qtl   = qth + QSZ;
    __bf16* kth   = qtl + QSZ;
    __bf16* vb    = kth + QSZ;
    __bf16* Opart = vb + VSZ;
    float*  dpart = (float*)(Opart + 2 * VSZ);

    wconv<<<dim3(80), 256, 0, stream>>>(wq, wk, wv, wbf);
    qkv_mfma<<<dim3(64, 2, BS), 256, 0, stream>>>(x, wbf, bq, bk, bv,
                                                  qth, qtl, kth, vb);
    attn_mfma<<<dim3(64, 2, BS), 256, 0, stream>>>(qth, qtl, kth, vb, Opart, dpart);
    combine<<<dim3(BS * NI * NPIX / 1024), 256, 0, stream>>>(x, gamma, Opart, dpart, out);
}

// Round 7
// 172.918 us; speedup vs baseline: 2.8420x; 1.5800x over previous
//
#include <hip/hip_runtime.h>
#include <cstdint>
#include <cstddef>

#define NI   256
#define QKC  32
#define BS   4
#define NPIX 4096   // 64*64

typedef __bf16 bf16x8 __attribute__((ext_vector_type(8)));
typedef __bf16 bf16x4 __attribute__((ext_vector_type(4)));
typedef float  f32x16 __attribute__((ext_vector_type(16)));

__device__ inline f32x16 zero16() {
    f32x16 z;
    #pragma unroll
    for (int i = 0; i < 16; ++i) z[i] = 0.f;
    return z;
}

// ---------------- Kernel 0: W fp32 -> bf16, concat [320][256] ----------------
__global__ __launch_bounds__(256) void wconv(
    const float* __restrict__ wq, const float* __restrict__ wk,
    const float* __restrict__ wv, __bf16* __restrict__ wbf)
{
    int f = (blockIdx.x * 256 + threadIdx.x) * 4;
    int row = f >> 8, c = f & 255;
    const float* src = row < 32 ? wq + row * NI + c
                     : row < 64 ? wk + (row - 32) * NI + c
                                : wv + (row - 64) * NI + c;
    float4 v = *(const float4*)src;
    __align__(8) __bf16 o4[4] = {(__bf16)v.x, (__bf16)v.y, (__bf16)v.z, (__bf16)v.w};
    *(uint2*)(wbf + f) = *(const uint2*)o4;
}

// ---------------- Kernel 1: QKV projection as bf16 MFMA GEMM ----------------
// q: hi/lo split [b][n][32]; k: hi only [b][n][32]; v: bf16 [b][c][n].
__global__ __launch_bounds__(256) void qkv_mfma(
    const float* __restrict__ x, const __bf16* __restrict__ wbf,
    const float* __restrict__ bq, const float* __restrict__ bk,
    const float* __restrict__ bv,
    __bf16* __restrict__ qth, __bf16* __restrict__ qtl,
    __bf16* __restrict__ kth, __bf16* __restrict__ vb)
{
    __shared__ __align__(16) __bf16 Wl[160][72];
    __shared__ __align__(16) __bf16 xT[64][72];
    __shared__ float bls[160];

    const int t = threadIdx.x, w = t >> 6, lane = t & 63;
    const int l31 = lane & 31, h = lane >> 5;
    const int b = blockIdx.z, hb = blockIdx.y, n0 = blockIdx.x * 64;

    if (t < 160) {
        int och = hb * 160 + t;
        bls[t] = och < 32 ? bq[och] : och < 64 ? bk[och - 32] : bv[och - 64];
    }

    f32x16 acc[3] = {zero16(), zero16(), zero16()};

    for (int kc = 0; kc < 4; ++kc) {
        __syncthreads();
        #pragma unroll
        for (int i = 0; i < 5; ++i) {          // stage W chunk 160x64
            int e = t + 256 * i; int row = e >> 3, ch = e & 7;
            *(uint4*)&Wl[row][ch * 8] =
                *(const uint4*)(wbf + ((size_t)(hb * 160 + row)) * NI + kc * 64 + ch * 8);
        }
        {   // stage x chunk transposed 64n x 64c via 4x4 micro-tiles
            int n4 = (t & 15) * 4, c4 = (t >> 4) * 4;
            float4 xv[4];
            #pragma unroll
            for (int j = 0; j < 4; ++j)
                xv[j] = *(const float4*)(x + ((size_t)(b * NI) + kc * 64 + c4 + j) * NPIX + n0 + n4);
            #pragma unroll
            for (int i = 0; i < 4; ++i) {
                __align__(8) __bf16 r4[4] = {
                    (__bf16)((&xv[0].x)[i]), (__bf16)((&xv[1].x)[i]),
                    (__bf16)((&xv[2].x)[i]), (__bf16)((&xv[3].x)[i])};
                *(uint2*)&xT[n4 + i][c4] = *(const uint2*)r4;
            }
        }
        __syncthreads();

        #pragma unroll
        for (int kk = 0; kk < 4; ++kk) {
            bf16x8 xf0 = *(const bf16x8*)&xT[l31][kk * 16 + 8 * h];
            bf16x8 xf1 = *(const bf16x8*)&xT[32 + l31][kk * 16 + 8 * h];
            #pragma unroll
            for (int jj = 0; jj < 3; ++jj) {
                int j = w + 4 * jj;
                if (j < 10) {                  // wave-uniform
                    int nt = j & 1, otl = j >> 1;
                    bf16x8 wf = *(const bf16x8*)&Wl[otl * 32 + l31][kk * 16 + 8 * h];
                    bf16x8 xf = nt ? xf1 : xf0;
                    if (hb == 0 && otl < 2)
                        acc[jj] = __builtin_amdgcn_mfma_f32_32x32x16_bf16(xf, wf, acc[jj], 0, 0, 0);
                    else
                        acc[jj] = __builtin_amdgcn_mfma_f32_32x32x16_bf16(wf, xf, acc[jj], 0, 0, 0);
                }
            }
        }
    }

    #pragma unroll
    for (int jj = 0; jj < 3; ++jj) {
        int j = w + 4 * jj;
        if (j >= 10) continue;
        int nt = j & 1, otl = j >> 1;
        int gt = hb * 5 + otl;
        const f32x16& A = acc[jj];
        if (gt < 2) {                          // q (hi+lo) or k (hi only), [b][n][32]
            __bf16* dh = gt == 0 ? qth : kth;
            float bias = bls[otl * 32 + l31];
            #pragma unroll
            for (int r = 0; r < 16; ++r) {
                int rit = (r & 3) + 8 * (r >> 2) + 4 * h;
                int n = n0 + nt * 32 + rit;
                float val = A[r] + bias;
                __bf16 hh = (__bf16)val;
                size_t idx = ((size_t)b * NPIX + n) * QKC + l31;
                dh[idx] = hh;
                if (gt == 0) qtl[idx] = (__bf16)(val - (float)hh);
            }
        } else {                               // v -> bf16 [b][c][n]
            #pragma unroll
            for (int r = 0; r < 16; ++r) {
                int rit = (r & 3) + 8 * (r >> 2) + 4 * h;
                int loc = otl * 32 + rit;
                int c = hb * 160 + loc - 64;
                float val = A[r] + bls[loc];
                vb[((size_t)(b * NI) + c) * NPIX + n0 + nt * 32 + l31] = (__bf16)val;
            }
        }
    }
}

// ---------------- Kernel 2: attention, NO K/V staging ----------------
// grid (64 n-tiles, 2 k-halves, 4 b) = 512 blocks of 256 thr.
// K and V fragments load DIRECTLY from global (qkv wrote fragment-friendly
// layouts; all reads L2-resident). LDS only holds the P round-trip (9 KB) ->
// plain-VGPR loads stay in flight across the two s_barriers, no spill.
__global__ __launch_bounds__(256) void attn_mfma(
    const __bf16* __restrict__ qth, const __bf16* __restrict__ qtl,
    const __bf16* __restrict__ kth, const __bf16* __restrict__ vb,
    __bf16* __restrict__ Opart, float* __restrict__ dpart)
{
    __shared__ __align__(16) __bf16 pt_s[64][72];   // 9216 B
    __shared__ float dbuf[4][36];                   // 576 B

    const int t    = threadIdx.x;
    const int b    = blockIdx.z;
    const int ksp  = blockIdx.y;
    const int n0   = blockIdx.x * 64;
    const int w    = t >> 6;
    const int lane = t & 63;
    const int l31  = lane & 31;
    const int h    = lane >> 5;
    const int sr   = w & 1, sc = w >> 1;
    const int mbase = ksp * (NPIX / 2);

    // q fragments (persistent)
    const size_t qrow = ((size_t)b * NPIX + n0 + 32 * sr + l31) * QKC;
    bf16x8 qh0 = *(const bf16x8*)(qth + qrow + 8 * h);
    bf16x8 qh1 = *(const bf16x8*)(qth + qrow + 16 + 8 * h);
    bf16x8 ql0 = *(const bf16x8*)(qtl + qrow + 8 * h);
    bf16x8 ql1 = *(const bf16x8*)(qtl + qrow + 16 + 8 * h);

    // direct-fragment base pointers
    const __bf16* kbase  = kth + ((size_t)b * NPIX + mbase + 32 * sc + l31) * QKC + 8 * h;
    const __bf16* vbase0 = vb + ((size_t)(b * NI) + 64 * w + l31) * NPIX + mbase + 8 * h;
    const __bf16* vbase1 = vbase0 + (size_t)32 * NPIX;

    bf16x8 ones;
    #pragma unroll
    for (int i = 0; i < 8; ++i) ones[i] = (__bf16)1.0f;

    f32x16 a00 = zero16(), a01 = zero16(), a10 = zero16(), a11 = zero16();
    f32x16 d = zero16();

    const int NIT = NPIX / 2 / 64;
    bf16x8 kh0 = *(const bf16x8*)kbase;
    bf16x8 kh1 = *(const bf16x8*)(kbase + 16);

    for (int mt = 0; mt < NIT; ++mt) {
        // ---- S quadrant: (qh+ql) x k, 4 MFMA ----
        f32x16 s = zero16();
        s = __builtin_amdgcn_mfma_f32_32x32x16_bf16(qh0, kh0, s, 0, 0, 0);
        s = __builtin_amdgcn_mfma_f32_32x32x16_bf16(qh1, kh1, s, 0, 0, 0);
        s = __builtin_amdgcn_mfma_f32_32x32x16_bf16(ql0, kh0, s, 0, 0, 0);
        s = __builtin_amdgcn_mfma_f32_32x32x16_bf16(ql1, kh1, s, 0, 0, 0);

        // prefetch next-iter K + this-iter V fragments (no barrier dependency)
        if (mt < NIT - 1) {
            const __bf16* kp = kbase + (size_t)(mt + 1) * 64 * QKC;
            kh0 = *(const bf16x8*)kp;
            kh1 = *(const bf16x8*)(kp + 16);
        }
        bf16x8 vf0[4], vf1[4];
        #pragma unroll
        for (int ks = 0; ks < 4; ++ks) {
            vf0[ks] = *(const bf16x8*)(vbase0 + (size_t)mt * 64 + ks * 16);
            vf1[ks] = *(const bf16x8*)(vbase1 + (size_t)mt * 64 + ks * 16);
        }

        #pragma unroll
        for (int r = 0; r < 16; ++r) {
            int rit = (r & 3) + 8 * (r >> 2) + 4 * h;
            pt_s[32 * sr + rit][32 * sc + l31] = (__bf16)__expf(s[r]);
        }
        __syncthreads();                       // pt ready

        #pragma unroll
        for (int ks = 0; ks < 4; ++ks) {
            bf16x8 pa0 = *(const bf16x8*)&pt_s[l31][ks * 16 + 8 * h];
            bf16x8 pa1 = *(const bf16x8*)&pt_s[32 + l31][ks * 16 + 8 * h];
            if ((ks >> 1) == sc)
                d = __builtin_amdgcn_mfma_f32_32x32x16_bf16(sr ? pa1 : pa0, ones, d, 0, 0, 0);
            a00 = __builtin_amdgcn_mfma_f32_32x32x16_bf16(pa0, vf0[ks], a00, 0, 0, 0);
            a10 = __builtin_amdgcn_mfma_f32_32x32x16_bf16(pa1, vf0[ks], a10, 0, 0, 0);
            a01 = __builtin_amdgcn_mfma_f32_32x32x16_bf16(pa0, vf1[ks], a01, 0, 0, 0);
            a11 = __builtin_amdgcn_mfma_f32_32x32x16_bf16(pa1, vf1[ks], a11, 0, 0, 0);
        }
        __syncthreads();                       // pt consumed
    }

    // ---- epilogue: d partials via LDS, direct Opart stores ----
    if (l31 == 0) {
        #pragma unroll
        for (int r = 0; r < 16; ++r) {
            int rit = (r & 3) + 8 * (r >> 2) + 4 * h;
            dbuf[w][rit] = d[r];
        }
    }
    __syncthreads();
    if (w < 2 && l31 == 0) {
        size_t dbase = ((size_t)(ksp * BS + b)) * NPIX + n0 + 32 * w;
        #pragma unroll
        for (int r = 0; r < 16; ++r) {
            int rit = (r & 3) + 8 * (r >> 2) + 4 * h;
            dpart[dbase + rit] = dbuf[w][rit] + dbuf[w + 2][rit];
        }
    }

    // Opart[c][n]: each lane owns c = 64w+l31 (+32), q-rows in quads of 4
    size_t obase = (((size_t)(ksp * BS + b)) * NI + 64 * w + l31) * NPIX + n0;
    #pragma unroll
    for (int rq = 0; rq < 4; ++rq) {
        int nn = 8 * rq + 4 * h;
        __align__(8) __bf16 t00[4], t10[4], t01[4], t11[4];
        #pragma unroll
        for (int i = 0; i < 4; ++i) {
            t00[i] = (__bf16)a00[4 * rq + i];
            t10[i] = (__bf16)a10[4 * rq + i];
            t01[i] = (__bf16)a01[4 * rq + i];
            t11[i] = (__bf16)a11[4 * rq + i];
        }
        *(uint2*)(Opart + obase + nn)                       = *(const uint2*)t00;
        *(uint2*)(Opart + obase + 32 + nn)                  = *(const uint2*)t10;
        *(uint2*)(Opart + obase + (size_t)32 * NPIX + nn)      = *(const uint2*)t01;
        *(uint2*)(Opart + obase + (size_t)32 * NPIX + 32 + nn) = *(const uint2*)t11;
    }
}

// ---------------- Kernel 3: combine ----------------
__global__ __launch_bounds__(256) void combine(
    const float* __restrict__ x, const float* __restrict__ gamma,
    const __bf16* __restrict__ Opart, const float* __restrict__ dpart,
    float* __restrict__ out)
{
    int idx = (blockIdx.x * 256 + threadIdx.x) * 4;
    int n = idx & (NPIX - 1);
    int c = (idx >> 12) & (NI - 1);
    int b = idx >> 20;

    size_t o0 = (((size_t)(0 * BS + b)) * NI + c) * NPIX + n;
    size_t o1 = (((size_t)(1 * BS + b)) * NI + c) * NPIX + n;
    bf16x4 p0 = *(const bf16x4*)(Opart + o0);
    bf16x4 p1 = *(const bf16x4*)(Opart + o1);
    float4 da = *(const float4*)(dpart + ((size_t)(0 * BS + b)) * NPIX + n);
    float4 db = *(const float4*)(dpart + ((size_t)(1 * BS + b)) * NPIX + n);
    size_t xb = ((size_t)(b * NI) + c) * NPIX + n;
    float4 xv = *(const float4*)(x + xb);
    float g = gamma[c];

    float4 r;
    r.x = g * (((float)p0[0] + (float)p1[0]) / (da.x + db.x)) + xv.x;
    r.y = g * (((float)p0[1] + (float)p1[1]) / (da.y + db.y)) + xv.y;
    r.z = g * (((float)p0[2] + (float)p1[2]) / (da.z + db.z)) + xv.z;
    r.w = g * (((float)p0[3] + (float)p1[3]) / (da.w + db.w)) + xv.w;
    *(float4*)(out + xb) = r;
}

extern "C" void kernel_launch(void* const* d_in, const int* in_sizes, int n_in,
                              void* d_out, int out_size, void* d_ws, size_t ws_size,
                              hipStream_t stream)
{
    const float* x     = (const float*)d_in[0];
    const float* wq    = (const float*)d_in[1];
    const float* bq    = (const float*)d_in[2];
    const float* wk    = (const float*)d_in[3];
    const float* bk    = (const float*)d_in[4];
    const float* wv    = (const float*)d_in[5];
    const float* bv    = (const float*)d_in[6];
    const float* gamma = (const float*)d_in[7];
    float* out = (float*)d_out;

    const size_t WSZ = (size_t)320 * NI;
    const size_t QSZ = (size_t)BS * NPIX * QKC;
    const size_t VSZ = (size_t)BS * NI * NPIX;
    __bf16* wbf   = (__bf16*)d_ws;
    __bf16* qth   = wbf + WSZ;
    __bf16* qtl   = qth + QSZ;
    __bf16* kth   = qtl + QSZ;
    __bf16* vb    = kth + QSZ;
    __bf16* Opart = vb + VSZ;
    float*  dpart = (float*)(Opart + 2 * VSZ);

    wconv<<<dim3(80), 256, 0, stream>>>(wq, wk, wv, wbf);
    qkv_mfma<<<dim3(64, 2, BS), 256, 0, stream>>>(x, wbf, bq, bk, bv,
                                                  qth, qtl, kth, vb);
    attn_mfma<<<dim3(64, 2, BS), 256, 0, stream>>>(qth, qtl, kth, vb, Opart, dpart);
    combine<<<dim3(BS * NI * NPIX / 1024), 256, 0, stream>>>(x, gamma, Opart, dpart, out);
}